// Round 8
// baseline (275.703 us; speedup 1.0000x reference)
//
#include <hip/hip_runtime.h>
#include <cstdint>

// NNLS PGD step (all tensors FLOAT32, k int32):
//   new_X = relu(th1 @ Y + weight); Y_new = new_X + (k-1)/(k+2)*(new_X - X_old)
// out (f32) = [Y_new (KB) | new_X (KB) | k+1 (1) | weight (KB)].
//
// R7 (phase-overlap) — resubmission; previous round hit GPUAcquisitionTimeout
// before any measurement:
//  - Each block = TWO adjacent 128x64 tiles (same m0) in ONE 64-step
//    counted-vmcnt K-pipeline. Tile0's epilogue is split into 4 chunks woven
//    into tile1's K-loop (kt=34/40/46/52) so its HBM traffic overlaps
//    MFMA+staging. Iter after a chunk uses vmcnt(13) (chunk=10 ops + next
//    stage=3 stay outstanding; needed stage guaranteed retired in-order).
//  - XCD-bijective block remap f=(y*64+x) -> (m=f&7, n=f>>3): each XCD owns
//    one 256KB A-panel (L2-resident) and streams Yt once.
//  - ep buffer moved to dedicated LDS (staging bufs live during chunks).
//  - conv + swizzled ws layout unchanged from R5.

#define KDIM 1024
#define NDIM 8192
#define KB_ELEMS (1024UL * 8192UL)
#define YT_BYTES (8192UL * 1024UL * 2UL) /* 16 MiB */
#define AB_BYTES (1024UL * 1024UL * 2UL) /*  2 MiB */
#define WS_NEED (YT_BYTES + AB_BYTES)

typedef short short8 __attribute__((ext_vector_type(8)));
typedef float f32x4 __attribute__((ext_vector_type(4)));

struct __attribute__((aligned(4))) f4u { float x, y, z, w; };  // 4B-aligned 16B store

__device__ __forceinline__ uint32_t pk2(float a, float b) {
  uint32_t ua = __builtin_bit_cast(uint32_t, a) + 0x8000u;
  uint32_t ub = __builtin_bit_cast(uint32_t, b) + 0x8000u;
  return (ua >> 16) | (ub & 0xFFFF0000u);
}

__device__ __forceinline__ void ldsload16(const void* g, void* l) {
  __builtin_amdgcn_global_load_lds(
      (const __attribute__((address_space(1))) uint32_t*)g,
      (__attribute__((address_space(3))) uint32_t*)l, 16, 0, 0);
}

// ---------------- K1: convert into swizzled bf16 workspace ----------------
// blocks 0..1023:   Y -> Yt[kt][n][32] bf16, 16B slots permuted by (n>>1)&3
// blocks 1024..1151: th1 -> A[kt][m][32] bf16, slots permuted by (m>>1)&3
__global__ __launch_bounds__(256) void nnls_conv(
    const float* __restrict__ th1, const float* __restrict__ Y,
    char* __restrict__ ws)
{
  unsigned short* yt  = (unsigned short*)ws;
  unsigned short* abf = (unsigned short*)(ws + YT_BYTES);
  const int tid = threadIdx.x;
  if (blockIdx.x < 1024) {
    const int kt = blockIdx.x >> 5;            // 0..31
    const int n  = (blockIdx.x & 31) * 256 + tid;
    const float* src = Y + (size_t)kt * 32 * NDIM + n;  // lanes: n consecutive
    float v[32];
#pragma unroll
    for (int r = 0; r < 32; ++r) v[r] = src[(size_t)r * NDIM];
    __attribute__((aligned(16))) uint32_t o[16];
#pragma unroll
    for (int r = 0; r < 16; ++r) o[r] = pk2(v[2 * r], v[2 * r + 1]);
    const int perm = (n >> 1) & 3;
    uint4* dst = (uint4*)(yt + ((size_t)kt * NDIM + n) * 32);  // 64B/thread, contig
    const uint4* o4 = (const uint4*)o;
#pragma unroll
    for (int q = 0; q < 4; ++q) dst[q ^ perm] = o4[q];
  } else {
    const int id = (blockIdx.x - 1024) * 256 + tid;  // 0..32767
    const int kt = id >> 10, m = id & 1023;          // lanes: m consecutive
    const float4* s4 = (const float4*)(th1 + (size_t)m * KDIM + kt * 32);
    __attribute__((aligned(16))) uint32_t o[16];
#pragma unroll
    for (int q = 0; q < 8; ++q) {
      const float4 v = s4[q];
      o[2 * q]     = pk2(v.x, v.y);
      o[2 * q + 1] = pk2(v.z, v.w);
    }
    const int perm = (m >> 1) & 3;
    uint4* dst = (uint4*)(abf + ((size_t)kt * KDIM + m) * 32);  // contig stores
    const uint4* o4 = (const uint4*)o;
#pragma unroll
    for (int q = 0; q < 4; ++q) dst[q ^ perm] = o4[q];
  }
}

// ---------------- K2: 2-tile GEMM with interleaved epilogue ----------------
// Super-block: 128m x (2x64n), 256 thr = 4 waves (2m x 2n), wave tile 64x32.
// grid (64,8) remapped f->(m=f&7, n=f>>3): 512 blocks, 2/CU, XCD-local A.
// 64-step 3-buf counted-vmcnt pipeline; tile0 epilogue chunks at kt=34..52.
__global__ __launch_bounds__(256, 2) void nnls_gemm7(
    const char* __restrict__ ws, const float* __restrict__ xold,
    const int* __restrict__ kin, const float* __restrict__ weight,
    float* __restrict__ out)
{
  const char* yt = ws;
  const char* ab = ws + YT_BYTES;
  __shared__ __align__(16) char smem[46080];
  // bufs p@p*12288 (As 8KB | Bs 4KB); ep region @36864 (4 x 2304B, wave-private)

  const int tid  = threadIdx.x;
  const int lane = tid & 63;
  const int w    = tid >> 6;            // 0..3
  const int wm = w >> 1, wn = w & 1;    // 2m x 2n wave grid
  const int quad = lane >> 4, nl = lane & 15;

  const int f  = blockIdx.y * 64 + blockIdx.x;  // flat dispatch id
  const int m0 = (f & 7) * 128;                 // XCD-bijective: XCD owns one A-panel
  const int nx = f >> 3;                        // 0..63 -> two n-tiles
  const int n0a = nx * 128, n0b = nx * 128 + 64;

  // staging sources: per-lane = wave-uniform base + lane*16 (1KB/instr)
  const char* ag = ab + (size_t)m0 * 64 + w * 1024 + lane * 16;
  const char* bg = yt + (size_t)(nx * 128) * 64 + w * 1024 + lane * 16;

  // stage k-step kt2 (0..63): tile = kt2>>5 (n-offset), k = kt2&31, buf = kt2%3
  auto stage = [&](int kt2) {
    const char* a2 = ag + (size_t)(kt2 & 31) * 65536;                       // A k-slice
    const char* b2 = bg + (size_t)(kt2 & 31) * 524288 + (kt2 >> 5) * 4096;  // Yt k-slice + tile
    char* d = smem + (kt2 % 3) * 12288;
    ldsload16(a2,        d + w * 1024);
    ldsload16(a2 + 4096, d + 4096 + w * 1024);
    ldsload16(b2,        d + 8192 + w * 1024);
  };

  stage(0);   // prologue: steps 0,1 in flight
  stage(1);

  f32x4 accA[4][2] = {}, accB[4][2] = {};
  // swizzled frag slot: physical 16B slot = quad ^ ((row>>1)&3)
  const int fro = (quad ^ ((nl >> 1) & 3)) * 8;  // ushort offset

  const float kf  = (float)kin[0];
  const float mom = (kf - 1.0f) / (kf + 2.0f);
  float* ep = (float*)(smem + 36864) + w * 576;  // 16 rows x 36 f32, wave-private
  const int rl = lane >> 3;  // epilogue read row-in-group 0..7
  const int cc = lane & 7;   // epilogue col quarter (x4 floats)

  // one epilogue chunk (i = acc row-chunk, literal at every use site)
#define EPI_CHUNK(i, ACC, N0T)                                                  \
  {                                                                             \
    const int mgb = m0 + wm * 64 + (i) * 16;                                    \
    size_t idxs[2]; float4 wv[2], xo[2];                                        \
    _Pragma("unroll")                                                           \
    for (int t = 0; t < 2; ++t) {                                               \
      idxs[t] = (size_t)(mgb + t * 8 + rl) * NDIM + (N0T) + wn * 32 + cc * 4;   \
      wv[t] = *(const float4*)&weight[idxs[t]];                                 \
      xo[t] = *(const float4*)&xold[idxs[t]];                                   \
    }                                                                           \
    _Pragma("unroll")                                                           \
    for (int j = 0; j < 2; ++j)                                                 \
      _Pragma("unroll")                                                         \
      for (int r = 0; r < 4; ++r)                                               \
        ep[(quad * 4 + r) * 36 + j * 16 + nl] = ACC[i][j][r];                   \
    _Pragma("unroll")                                                           \
    for (int t = 0; t < 2; ++t) {                                               \
      const float4 cv = *(const float4*)&ep[(t * 8 + rl) * 36 + cc * 4];        \
      const size_t idx = idxs[t];                                               \
      float4 nx_, yn;                                                           \
      nx_.x = fmaxf(cv.x + wv[t].x, 0.0f); nx_.y = fmaxf(cv.y + wv[t].y, 0.0f); \
      nx_.z = fmaxf(cv.z + wv[t].z, 0.0f); nx_.w = fmaxf(cv.w + wv[t].w, 0.0f); \
      yn.x = nx_.x + mom * (nx_.x - xo[t].x); yn.y = nx_.y + mom * (nx_.y - xo[t].y); \
      yn.z = nx_.z + mom * (nx_.z - xo[t].z); yn.w = nx_.w + mom * (nx_.w - xo[t].w); \
      *(float4*)&out[idx] = yn;                                                 \
      *(float4*)&out[KB_ELEMS + idx] = nx_;                                     \
      f4u s_; s_.x = wv[t].x; s_.y = wv[t].y; s_.z = wv[t].z; s_.w = wv[t].w;   \
      *(f4u*)&out[2 * KB_ELEMS + 1 + idx] = s_;                                 \
    }                                                                           \
  }

#pragma unroll
  for (int kt = 0; kt < 64; ++kt) {
    // counted waits: steady vmcnt(3); after a chunk iter the queue holds
    // [neededStage(3)][chunk(10)][nextStage(3)] -> vmcnt(13) retires neededStage
    if (kt == 63)      { asm volatile("s_waitcnt vmcnt(0)"  ::: "memory"); }
    else if (kt == 35 || kt == 41 || kt == 47 || kt == 53)
                       { asm volatile("s_waitcnt vmcnt(13)" ::: "memory"); }
    else               { asm volatile("s_waitcnt vmcnt(3)"  ::: "memory"); }
    __builtin_amdgcn_s_barrier();  // step-kt data in LDS for all waves; fences
                                   // iter kt-1 reads of buf[(kt+2)%3]

    // tile0 epilogue chunks, woven into tile1's K-loop (accA final since kt=31)
    if (kt == 34)      EPI_CHUNK(0, accA, n0a)
    else if (kt == 40) EPI_CHUNK(1, accA, n0a)
    else if (kt == 46) EPI_CHUNK(2, accA, n0a)
    else if (kt == 52) EPI_CHUNK(3, accA, n0a)

    if (kt < 62) stage(kt + 2);

    const unsigned short* Asp = (const unsigned short*)(smem + (kt % 3) * 12288);
    const unsigned short* Bsp = Asp + 4096;  // +8192 B
    short8 af[4], bf[2];
#pragma unroll
    for (int i = 0; i < 4; ++i)
      af[i] = *(const short8*)&Asp[(wm * 64 + i * 16 + nl) * 32 + fro];
#pragma unroll
    for (int j = 0; j < 2; ++j)
      bf[j] = *(const short8*)&Bsp[(wn * 32 + j * 16 + nl) * 32 + fro];
    if (kt < 32) {
#pragma unroll
      for (int i = 0; i < 4; ++i)
#pragma unroll
        for (int j = 0; j < 2; ++j)
          accA[i][j] = __builtin_amdgcn_mfma_f32_16x16x32_bf16(af[i], bf[j], accA[i][j], 0, 0, 0);
    } else {
#pragma unroll
      for (int i = 0; i < 4; ++i)
#pragma unroll
        for (int j = 0; j < 2; ++j)
          accB[i][j] = __builtin_amdgcn_mfma_f32_16x16x32_bf16(af[i], bf[j], accB[i][j], 0, 0, 0);
    }
  }

  // tail: tile1 epilogue (exposed half)
  EPI_CHUNK(0, accB, n0b)
  EPI_CHUNK(1, accB, n0b)
  EPI_CHUNK(2, accB, n0b)
  EPI_CHUNK(3, accB, n0b)
#undef EPI_CHUNK

  if (f == 0 && tid == 0)
    out[2 * KB_ELEMS] = (float)(kin[0] + 1);
}

// ---------------- fallback: single-kernel path (ws too small) ----------------
#define LDA 40
__global__ __launch_bounds__(512, 4) void nnls_gemm_v1(
    const float* __restrict__ th1, const float* __restrict__ Y,
    const float* __restrict__ xold, const int* __restrict__ kin,
    const float* __restrict__ weight, float* __restrict__ out)
{
  __shared__ __align__(16) char smem[40960];
  unsigned short* As0 = (unsigned short*)smem;
  unsigned short* Bs0 = (unsigned short*)(smem + 10240);
  unsigned short* As1 = (unsigned short*)(smem + 20480);
  unsigned short* Bs1 = (unsigned short*)(smem + 30720);

  const int tid  = threadIdx.x;
  const int lane = tid & 63;
  const int w    = tid >> 6;
  const int wm = w >> 1, wn = w & 1;
  const int quad = lane >> 4, nl = lane & 15;
  const int m0 = blockIdx.y * 128;
  const int n0 = blockIdx.x * 128;
  const int ar = tid >> 3;
  const int ac = tid & 7;
  const float* abase = th1 + (size_t)(m0 + ar) * KDIM + ac * 4;
  const int bn = tid & 127;
  const int bk = (tid >> 7) * 8;
  const float* ybase = Y + (size_t)bk * NDIM + n0 + bn;

  float4 abv[2];
  float  yb[8];
  abv[0] = *(const float4*)(abase);
  abv[1] = *(const float4*)(abase + (size_t)64 * KDIM);
#pragma unroll
  for (int r = 0; r < 8; ++r) yb[r] = ybase[(size_t)r * NDIM];

  f32x4 acc[2][4] = {};

#pragma unroll 2
  for (int kt = 0; kt < 32; ++kt) {
    unsigned short* Asp = (kt & 1) ? As1 : As0;
    unsigned short* Bsp = (kt & 1) ? Bs1 : Bs0;
    {
      uint2 d0; d0.x = pk2(abv[0].x, abv[0].y); d0.y = pk2(abv[0].z, abv[0].w);
      *(uint2*)&Asp[ar * LDA + ac * 4] = d0;
      uint2 d1; d1.x = pk2(abv[1].x, abv[1].y); d1.y = pk2(abv[1].z, abv[1].w);
      *(uint2*)&Asp[(ar + 64) * LDA + ac * 4] = d1;
      uint4 e;
      e.x = pk2(yb[0], yb[1]); e.y = pk2(yb[2], yb[3]);
      e.z = pk2(yb[4], yb[5]); e.w = pk2(yb[6], yb[7]);
      *(uint4*)&Bsp[bn * LDA + bk] = e;
    }
    __syncthreads();
    if (kt < 31) {
      const float* an = abase + (kt + 1) * 32;
      abv[0] = *(const float4*)(an);
      abv[1] = *(const float4*)(an + (size_t)64 * KDIM);
      const float* yn = ybase + (size_t)((kt + 1) * 32) * NDIM;
#pragma unroll
      for (int r = 0; r < 8; ++r) yb[r] = yn[(size_t)r * NDIM];
    }
    short8 af[2], bf[4];
#pragma unroll
    for (int i = 0; i < 2; ++i)
      af[i] = *(const short8*)&Asp[(wm * 32 + i * 16 + nl) * LDA + quad * 8];
#pragma unroll
    for (int j = 0; j < 4; ++j)
      bf[j] = *(const short8*)&Bsp[(wn * 64 + j * 16 + nl) * LDA + quad * 8];
#pragma unroll
    for (int i = 0; i < 2; ++i)
#pragma unroll
      for (int j = 0; j < 4; ++j)
        acc[i][j] = __builtin_amdgcn_mfma_f32_16x16x32_bf16(af[i], bf[j], acc[i][j], 0, 0, 0);
    __syncthreads();
  }
  __syncthreads();

  const float kf  = (float)kin[0];
  const float mom = (kf - 1.0f) / (kf + 2.0f);
  float* ep = (float*)smem + w * 1088;
  const int u  = lane >> 4;
  const int mc = lane & 15;
#pragma unroll
  for (int i = 0; i < 2; ++i) {
#pragma unroll
    for (int j = 0; j < 4; ++j)
#pragma unroll
      for (int r = 0; r < 4; ++r)
        ep[(quad * 4 + r) * 68 + (j * 16 + nl)] = acc[i][j][r];
    const int mgb = m0 + wm * 32 + i * 16;
#pragma unroll
    for (int t = 0; t < 4; ++t) {
      const int row = t * 4 + u;
      const float4 cv = *(const float4*)&ep[row * 68 + mc * 4];
      const int ng = n0 + wn * 64 + mc * 4;
      const size_t idx = (size_t)(mgb + row) * NDIM + ng;
      const float4 wv = *(const float4*)&weight[idx];
      const float4 xo = *(const float4*)&xold[idx];
      float4 nx, yn;
      nx.x = fmaxf(cv.x + wv.x, 0.0f); nx.y = fmaxf(cv.y + wv.y, 0.0f);
      nx.z = fmaxf(cv.z + wv.z, 0.0f); nx.w = fmaxf(cv.w + wv.w, 0.0f);
      yn.x = nx.x + mom * (nx.x - xo.x); yn.y = nx.y + mom * (nx.y - xo.y);
      yn.z = nx.z + mom * (nx.z - xo.z); yn.w = nx.w + mom * (nx.w - xo.w);
      *(float4*)&out[idx] = yn;
      *(float4*)&out[KB_ELEMS + idx] = nx;
      f4u s; s.x = wv.x; s.y = wv.y; s.z = wv.z; s.w = wv.w;
      *(f4u*)&out[2 * KB_ELEMS + 1 + idx] = s;
    }
  }
  if (blockIdx.x == 0 && blockIdx.y == 0 && tid == 0)
    out[2 * KB_ELEMS] = (float)(kin[0] + 1);
}

extern "C" void kernel_launch(void* const* d_in, const int* in_sizes, int n_in,
                              void* d_out, int out_size, void* d_ws, size_t ws_size,
                              hipStream_t stream) {
  const float* th1  = (const float*)d_in[0];
  const float* Y    = (const float*)d_in[1];
  const float* xold = (const float*)d_in[2];
  const int*   kin  = (const int*)d_in[3];
  const float* wgt  = (const float*)d_in[4];
  float* out = (float*)d_out;

  if (d_ws != nullptr && ws_size >= WS_NEED) {
    nnls_conv<<<1152, 256, 0, stream>>>(th1, Y, (char*)d_ws);
    nnls_gemm7<<<dim3(64, 8), 256, 0, stream>>>(
        (const char*)d_ws, xold, kin, wgt, out);
  } else {
    nnls_gemm_v1<<<dim3(NDIM / 128, KDIM / 128), 512, 0, stream>>>(
        th1, Y, xold, kin, wgt, out);
  }
}